// Round 2
// baseline (1934.772 us; speedup 1.0000x reference)
//
#include <hip/hip_runtime.h>
#include <hip/hip_bf16.h>

// All float tensors are float32 (per reference setup_inputs); indices int32.

// ---------------------------------------------------------------------------
// K0: tiny prep — w_er[h0][i] = sum_d attn_r[h0,d]*W_dst[h0*32+d, i]  (256 vals)
//     Wn = softmax(fc_W, axis=1) (16 vals), fb = fc_b (4 vals)
// ---------------------------------------------------------------------------
__global__ void k_prep(const float* __restrict__ Wdst,
                       const float* __restrict__ attn_r,
                       const float* __restrict__ fcW,
                       const float* __restrict__ fcb,
                       float* __restrict__ w_er, float* __restrict__ Wn,
                       float* __restrict__ fb) {
    int t = threadIdx.x;
    if (t < 256) {
        int h0 = t >> 7, i = t & 127;
        float s = 0.f;
        for (int d = 0; d < 32; ++d)
            s += attn_r[h0 * 32 + d] * Wdst[(size_t)(h0 * 32 + d) * 128 + i];
        w_er[t] = s;
    }
    if (t < 16) {
        int oh = t >> 2, k = t & 3;
        float w[4], m = -1e30f;
        for (int j = 0; j < 4; ++j) {
            w[j] = fcW[oh * 4 + j];
            m = fmaxf(m, w[j]);
        }
        float s = 0.f;
        for (int j = 0; j < 4; ++j) s += __expf(w[j] - m);
        Wn[t] = __expf(w[k] - m) / s;
    }
    if (t < 4) fb[t] = fcb[t];
}

// ---------------------------------------------------------------------------
// K1: feat_src projection + el.  One wave per row (row = n*2 + h1), lane = o
//     (o = h0*32 + d).  feat[row*64+o] = dot(hier1[row,:], Wsrc[o,:]) (K=128).
//     el[row*2+h0] = sum_d feat * attn_l[h0,d]   (32-lane shuffle reduce).
// ---------------------------------------------------------------------------
__global__ void k_feat(const float* __restrict__ hier1,
                       const float* __restrict__ Wsrc,
                       const float* __restrict__ attn_l,
                       float* __restrict__ feat, float* __restrict__ el,
                       int nrows) {
    int wave = (blockIdx.x * blockDim.x + threadIdx.x) >> 6;
    int lane = threadIdx.x & 63;
    if (wave >= nrows) return;
    const float4* hp = reinterpret_cast<const float4*>(hier1 + (size_t)wave * 128);
    const float4* wp = reinterpret_cast<const float4*>(Wsrc + (size_t)lane * 128);
    float acc = 0.f;
#pragma unroll
    for (int k = 0; k < 32; ++k) {
        float4 h = hp[k];
        float4 w = wp[k];
        acc = fmaf(h.x, w.x, acc);
        acc = fmaf(h.y, w.y, acc);
        acc = fmaf(h.z, w.z, acc);
        acc = fmaf(h.w, w.w, acc);
    }
    feat[(size_t)wave * 64 + lane] = acc;
    float v = acc * attn_l[lane];
#pragma unroll
    for (int m = 16; m >= 1; m >>= 1) v += __shfl_xor(v, m, 64);
    if ((lane & 31) == 0) el[wave * 2 + (lane >> 5)] = v;
}

// ---------------------------------------------------------------------------
// K2: er[n,h0] = sum_i hier0[n,i] * w_er[h0,i].  One wave per node; lane
//     handles i = 2*lane..2*lane+1; full 64-lane shuffle reduce.
// ---------------------------------------------------------------------------
__global__ void k_er(const float* __restrict__ hier0,
                     const float* __restrict__ w_er, float* __restrict__ er,
                     int n) {
    int wave = (blockIdx.x * blockDim.x + threadIdx.x) >> 6;
    int lane = threadIdx.x & 63;
    if (wave >= n) return;
    float2 h = *reinterpret_cast<const float2*>(hier0 + (size_t)wave * 128 + lane * 2);
    float2 w0 = *reinterpret_cast<const float2*>(w_er + lane * 2);
    float2 w1 = *reinterpret_cast<const float2*>(w_er + 128 + lane * 2);
    float p0 = h.x * w0.x + h.y * w0.y;
    float p1 = h.x * w1.x + h.y * w1.y;
#pragma unroll
    for (int m = 32; m >= 1; m >>= 1) {
        p0 += __shfl_xor(p0, m, 64);
        p1 += __shfl_xor(p1, m, 64);
    }
    if (lane == 0) {
        er[wave * 2] = p0;
        er[wave * 2 + 1] = p1;
    }
}

// ---------------------------------------------------------------------------
// K3: edge pass.  128 threads per edge: t = k*32 + dd  (k = h1*2+h0).
//     ee = exp(lrelu(el[src,k] + er[dst,h0]))  (softmax shift skipped:
//     |e| <~ 3 statistically, exp can't overflow, softmax shift-invariant)
//     denom[dst,k] += ee  (1 lane per k);  numer[dst, t] += ee * feat[src, t].
// ---------------------------------------------------------------------------
__global__ void k_edge(const int* __restrict__ src, const int* __restrict__ dst,
                       const float* __restrict__ el, const float* __restrict__ er,
                       const float* __restrict__ feat,
                       float* __restrict__ numer, float* __restrict__ denom,
                       int E) {
    int gid = blockIdx.x * blockDim.x + threadIdx.x;
    int e = gid >> 7;
    int t = gid & 127;
    if (e >= E) return;
    int s = src[e], d = dst[e];
    int k = t >> 5;
    float ev = el[s * 4 + k] + er[d * 2 + (k & 1)];
    ev = ev > 0.f ? ev : 0.2f * ev;
    float ee = __expf(ev);
    if ((t & 31) == 0) atomicAdd(denom + (size_t)d * 4 + k, ee);
    float f = feat[(size_t)s * 128 + t];
    atomicAdd(numer + (size_t)d * 128 + t, ee * f);
}

// ---------------------------------------------------------------------------
// K4: epilogue.  32 threads per node (dd = lane).  gat[k] = numer/denom + bias;
//     out[n,oh,dd] = sum_k gat[k]*Wn[oh,k] + fb[oh]  (f32 store).
// ---------------------------------------------------------------------------
__global__ void k_out(const float* __restrict__ numer,
                      const float* __restrict__ denom,
                      const float* __restrict__ bias,
                      const float* __restrict__ Wn, const float* __restrict__ fb,
                      float* __restrict__ out, int n) {
    int gid = blockIdx.x * blockDim.x + threadIdx.x;
    int node = gid >> 5;
    int dd = gid & 31;
    if (node >= n) return;
    float g[4];
#pragma unroll
    for (int k = 0; k < 4; ++k) {
        float den = denom[(size_t)node * 4 + k];
        float v = den > 0.f ? numer[(size_t)node * 128 + k * 32 + dd] / den : 0.f;
        g[k] = v + bias[(k & 1) * 32 + dd];
    }
#pragma unroll
    for (int oh = 0; oh < 4; ++oh) {
        float r = fb[oh];
#pragma unroll
        for (int k = 0; k < 4; ++k) r = fmaf(g[k], Wn[oh * 4 + k], r);
        out[(size_t)node * 128 + oh * 32 + dd] = r;
    }
}

// ---------------------------------------------------------------------------
extern "C" void kernel_launch(void* const* d_in, const int* in_sizes, int n_in,
                              void* d_out, int out_size, void* d_ws, size_t ws_size,
                              hipStream_t stream) {
    (void)n_in; (void)out_size; (void)ws_size;
    const float* hier1  = (const float*)d_in[0];
    const float* hier0  = (const float*)d_in[1];
    const int*   srcIdx = (const int*)d_in[2];
    const int*   dstIdx = (const int*)d_in[3];
    const float* Wsrc   = (const float*)d_in[4];
    const float* Wdst   = (const float*)d_in[5];
    const float* attn_l = (const float*)d_in[6];
    const float* attn_r = (const float*)d_in[7];
    const float* bias   = (const float*)d_in[8];
    const float* fcW    = (const float*)d_in[9];
    const float* fcb    = (const float*)d_in[10];
    float* out = (float*)d_out;

    const int Nsrc  = in_sizes[0] / 256;  // N_SRC (H1=2, IN1=128)
    const int Ndst  = in_sizes[1] / 128;  // N_DST (IN0=128)
    const int E     = in_sizes[2];
    const int nrows = Nsrc * 2;           // N_SRC * H1

    // ws layout (f32)
    float* feat  = (float*)d_ws;                  // nrows*64
    float* numer = feat  + (size_t)nrows * 64;    // Ndst*128
    float* el    = numer + (size_t)Ndst * 128;    // nrows*2
    float* er    = el    + (size_t)nrows * 2;     // Ndst*2
    float* den   = er    + (size_t)Ndst * 2;      // Ndst*4
    float* w_er  = den   + (size_t)Ndst * 4;      // 256
    float* Wn    = w_er + 256;                    // 16
    float* fb    = Wn + 16;                       // 4

    hipMemsetAsync(numer, 0, (size_t)Ndst * 128 * sizeof(float), stream);
    hipMemsetAsync(den,   0, (size_t)Ndst * 4 * sizeof(float), stream);

    k_prep<<<1, 256, 0, stream>>>(Wdst, attn_r, fcW, fcb, w_er, Wn, fb);

    k_feat<<<(nrows + 3) / 4, 256, 0, stream>>>(hier1, Wsrc, attn_l, feat, el, nrows);

    k_er<<<(Ndst + 3) / 4, 256, 0, stream>>>(hier0, w_er, er, Ndst);

    {
        long long tot = (long long)E * 128;
        int blocks = (int)((tot + 255) / 256);
        k_edge<<<blocks, 256, 0, stream>>>(srcIdx, dstIdx, el, er, feat, numer, den, E);
    }

    k_out<<<(Ndst * 32 + 255) / 256, 256, 0, stream>>>(numer, den, bias, Wn, fb, out, Ndst);
}

// Round 3
// 927.353 us; speedup vs baseline: 2.0863x; 2.0863x over previous
//
#include <hip/hip_runtime.h>

__device__ __forceinline__ float lrelu(float x) { return x > 0.f ? x : 0.2f * x; }

// ---------------------------------------------------------------------------
// K0: tiny prep — w_er[h0][i] = sum_d attn_r[h0,d]*W_dst[h0*32+d, i]  (256 vals)
//     Wn = softmax(fc_W, axis=1) (16 vals), fb = fc_b (4 vals)
// ---------------------------------------------------------------------------
__global__ void k_prep(const float* __restrict__ Wdst,
                       const float* __restrict__ attn_r,
                       const float* __restrict__ fcW,
                       const float* __restrict__ fcb,
                       float* __restrict__ w_er, float* __restrict__ Wn,
                       float* __restrict__ fb) {
    int t = threadIdx.x;
    if (t < 256) {
        int h0 = t >> 7, i = t & 127;
        float s = 0.f;
        for (int d = 0; d < 32; ++d)
            s += attn_r[h0 * 32 + d] * Wdst[(size_t)(h0 * 32 + d) * 128 + i];
        w_er[t] = s;
    }
    if (t < 16) {
        int oh = t >> 2, k = t & 3;
        float w[4], m = -1e30f;
        for (int j = 0; j < 4; ++j) {
            w[j] = fcW[oh * 4 + j];
            m = fmaxf(m, w[j]);
        }
        float s = 0.f;
        for (int j = 0; j < 4; ++j) s += __expf(w[j] - m);
        Wn[t] = __expf(w[k] - m) / s;
    }
    if (t < 4) fb[t] = fcb[t];
}

// ---------------------------------------------------------------------------
// K1: feat projection + el, LDS-tiled.
//   Block = 256 thr (4 waves), TILE = 32 rows (8 rows per wave).
//   Wsrc staged in LDS as float4 W[kk][o] (kk = k/4, o = output) so lane o's
//   ds_read_b128 is stride-16B across lanes -> conflict-free full width.
//   hier1 rows staged straight; per-row reads are same-address broadcasts.
// ---------------------------------------------------------------------------
__global__ __launch_bounds__(256) void k_feat(
        const float* __restrict__ hier1, const float* __restrict__ Wsrc,
        const float* __restrict__ attn_l,
        float* __restrict__ feat, float* __restrict__ el, int nrows) {
    __shared__ float4 Wlds[2048];   // [kk*64 + o]
    __shared__ float4 Hlds[1024];   // [r*32 + kk], r = local row 0..31
    int t = threadIdx.x;

    const float4* W4 = reinterpret_cast<const float4*>(Wsrc);
#pragma unroll
    for (int j = 0; j < 8; ++j) {
        int g = t + j * 256;                       // coalesced global f4 idx
        Wlds[(g & 31) * 64 + (g >> 5)] = W4[g];    // transpose into [kk][o]
    }
    int base = blockIdx.x * 32;
    const float4* H4 = reinterpret_cast<const float4*>(hier1);
#pragma unroll
    for (int j = 0; j < 4; ++j) {
        int idx = t + j * 256;                     // 0..1023
        int r = idx >> 5;
        if (base + r < nrows)
            Hlds[idx] = H4[(size_t)(base + r) * 32 + (idx & 31)];
    }
    __syncthreads();

    int w = t >> 6, o = t & 63;
    float al = attn_l[o];
    float acc[8];
#pragma unroll
    for (int j = 0; j < 8; ++j) acc[j] = 0.f;

    for (int kk = 0; kk < 32; ++kk) {
        float4 wv = Wlds[kk * 64 + o];
#pragma unroll
        for (int j = 0; j < 8; ++j) {
            float4 hv = Hlds[(w * 8 + j) * 32 + kk];
            acc[j] = fmaf(hv.x, wv.x,
                     fmaf(hv.y, wv.y,
                     fmaf(hv.z, wv.z,
                     fmaf(hv.w, wv.w, acc[j]))));
        }
    }

#pragma unroll
    for (int j = 0; j < 8; ++j) {
        int row = base + w * 8 + j;
        if (row < nrows) {
            feat[(size_t)row * 64 + o] = acc[j];
            float v = acc[j] * al;
#pragma unroll
            for (int m = 16; m >= 1; m >>= 1) v += __shfl_xor(v, m, 64);
            if ((o & 31) == 0) el[row * 2 + (o >> 5)] = v;
        }
    }
}

// ---------------------------------------------------------------------------
// K2: er[n,h0] = sum_i hier0[n,i] * w_er[h0,i].  One wave per node.
// ---------------------------------------------------------------------------
__global__ void k_er(const float* __restrict__ hier0,
                     const float* __restrict__ w_er, float* __restrict__ er,
                     int n) {
    int wave = (blockIdx.x * blockDim.x + threadIdx.x) >> 6;
    int lane = threadIdx.x & 63;
    if (wave >= n) return;
    float2 h = *reinterpret_cast<const float2*>(hier0 + (size_t)wave * 128 + lane * 2);
    float2 w0 = *reinterpret_cast<const float2*>(w_er + lane * 2);
    float2 w1 = *reinterpret_cast<const float2*>(w_er + 128 + lane * 2);
    float p0 = h.x * w0.x + h.y * w0.y;
    float p1 = h.x * w1.x + h.y * w1.y;
#pragma unroll
    for (int m = 32; m >= 1; m >>= 1) {
        p0 += __shfl_xor(p0, m, 64);
        p1 += __shfl_xor(p1, m, 64);
    }
    if (lane == 0) {
        er[wave * 2] = p0;
        er[wave * 2 + 1] = p1;
    }
}

// ---------------------------------------------------------------------------
// CSR build: histogram -> single-block scan -> scatter
// ---------------------------------------------------------------------------
__global__ void k_hist(const int* __restrict__ dst, int* __restrict__ deg, int E) {
    int e = blockIdx.x * blockDim.x + threadIdx.x;
    if (e < E) atomicAdd(&deg[dst[e]], 1);
}

__global__ __launch_bounds__(1024) void k_scan(
        const int* __restrict__ deg, int* __restrict__ off,
        int* __restrict__ cursor, int N) {
    __shared__ int wsum[16];
    int t = threadIdx.x;
    int chunk = (N + 1023) >> 10;
    int beg = t * chunk, end = min(beg + chunk, N);
    int s = 0;
    for (int i = beg; i < end; ++i) s += deg[i];

    int lane = t & 63, wid = t >> 6;
    int v = s;
#pragma unroll
    for (int m = 1; m < 64; m <<= 1) {
        int u = __shfl_up(v, m, 64);
        if (lane >= m) v += u;
    }
    if (lane == 63) wsum[wid] = v;
    __syncthreads();
    if (t < 16) {
        int ws = wsum[t];
#pragma unroll
        for (int m = 1; m < 16; m <<= 1) {
            int u = __shfl_up(ws, m, 64);
            if (t >= m) ws += u;
        }
        wsum[t] = ws;   // inclusive wave-sum prefix
    }
    __syncthreads();
    int excl = v - s + (wid > 0 ? wsum[wid - 1] : 0);
    for (int i = beg; i < end; ++i) {
        off[i] = excl;
        cursor[i] = excl;
        excl += deg[i];
    }
}

__global__ void k_scatter(const int* __restrict__ src, const int* __restrict__ dst,
                          int* __restrict__ cursor, int* __restrict__ ssrc, int E) {
    int e = blockIdx.x * blockDim.x + threadIdx.x;
    if (e >= E) return;
    int pos = atomicAdd(&cursor[dst[e]], 1);
    ssrc[pos] = src[e];
}

// ---------------------------------------------------------------------------
// K3: gather + fused epilogue.  One block (128 thr) per dst node.
//   t = k*32+dd (k = h1*2+h0).  Loop over the node's CSR edge list:
//   ee = exp(lrelu(el[s,k]+er[d,h0])) recomputed per lane (exp is cheap),
//   numer/denom in registers.  Then normalize + bias + softmaxed head-mix.
// ---------------------------------------------------------------------------
__global__ __launch_bounds__(128) void k_gather(
        const int* __restrict__ ssrc, const int* __restrict__ off,
        const int* __restrict__ deg,
        const float* __restrict__ el, const float* __restrict__ er,
        const float* __restrict__ feat, const float* __restrict__ bias,
        const float* __restrict__ Wn, const float* __restrict__ fb,
        float* __restrict__ out) {
    int d = blockIdx.x;
    int t = threadIdx.x;
    int k = t >> 5, dd = t & 31;
    int start = off[d], n = deg[d];
    float erk = er[d * 2 + (k & 1)];

    float acc = 0.f, den = 0.f;
    for (int i = 0; i < n; ++i) {
        int s = ssrc[start + i];
        float ee = __expf(lrelu(el[s * 4 + k] + erk));
        den += ee;
        acc = fmaf(ee, feat[(size_t)s * 128 + t], acc);
    }

    __shared__ float g[128];
    g[t] = (den > 0.f ? acc / den : 0.f) + bias[(k & 1) * 32 + dd];
    __syncthreads();

    int oh = k;
    float r = fb[oh];
#pragma unroll
    for (int kk = 0; kk < 4; ++kk) r = fmaf(g[kk * 32 + dd], Wn[oh * 4 + kk], r);
    out[(size_t)d * 128 + oh * 32 + dd] = r;
}

// ---------------------------------------------------------------------------
extern "C" void kernel_launch(void* const* d_in, const int* in_sizes, int n_in,
                              void* d_out, int out_size, void* d_ws, size_t ws_size,
                              hipStream_t stream) {
    (void)n_in; (void)out_size; (void)ws_size;
    const float* hier1  = (const float*)d_in[0];
    const float* hier0  = (const float*)d_in[1];
    const int*   srcIdx = (const int*)d_in[2];
    const int*   dstIdx = (const int*)d_in[3];
    const float* Wsrc   = (const float*)d_in[4];
    const float* Wdst   = (const float*)d_in[5];
    const float* attn_l = (const float*)d_in[6];
    const float* attn_r = (const float*)d_in[7];
    const float* bias   = (const float*)d_in[8];
    const float* fcW    = (const float*)d_in[9];
    const float* fcb    = (const float*)d_in[10];
    float* out = (float*)d_out;

    const int Nsrc  = in_sizes[0] / 256;  // N_SRC (H1=2, IN1=128)
    const int Ndst  = in_sizes[1] / 128;  // N_DST (IN0=128)
    const int E     = in_sizes[2];
    const int nrows = Nsrc * 2;           // N_SRC * H1

    // ws layout
    float* feat  = (float*)d_ws;                  // nrows*64
    float* el    = feat + (size_t)nrows * 64;     // nrows*2
    float* er    = el   + (size_t)nrows * 2;      // Ndst*2
    float* w_er  = er   + (size_t)Ndst * 2;       // 256
    float* Wn    = w_er + 256;                    // 16
    float* fb    = Wn + 16;                       // 4
    int*  deg    = (int*)(fb + 4);                // Ndst
    int*  off    = deg + Ndst;                    // Ndst
    int*  cursor = off + Ndst;                    // Ndst
    int*  ssrc   = cursor + Ndst;                 // E

    hipMemsetAsync(deg, 0, (size_t)Ndst * sizeof(int), stream);

    k_prep<<<1, 256, 0, stream>>>(Wdst, attn_r, fcW, fcb, w_er, Wn, fb);

    k_feat<<<(nrows + 31) / 32, 256, 0, stream>>>(hier1, Wsrc, attn_l, feat, el, nrows);

    k_er<<<(Ndst + 3) / 4, 256, 0, stream>>>(hier0, w_er, er, Ndst);

    k_hist<<<(E + 255) / 256, 256, 0, stream>>>(dstIdx, deg, E);

    k_scan<<<1, 1024, 0, stream>>>(deg, off, cursor, Ndst);

    k_scatter<<<(E + 255) / 256, 256, 0, stream>>>(srcIdx, dstIdx, cursor, ssrc, E);

    k_gather<<<Ndst, 128, 0, stream>>>(ssrc, off, deg, el, er, feat, bias, Wn, fb, out);
}

// Round 4
// 720.271 us; speedup vs baseline: 2.6862x; 1.2875x over previous
//
#include <hip/hip_runtime.h>

__device__ __forceinline__ float lrelu(float x) { return x > 0.f ? x : 0.2f * x; }

// ---------------------------------------------------------------------------
// K0: tiny prep — w_er[h0][i] = sum_d attn_r[h0,d]*W_dst[h0*32+d, i]  (256 vals)
//     Wn = softmax(fc_W, axis=1) (16 vals), fb = fc_b (4 vals)
// ---------------------------------------------------------------------------
__global__ void k_prep(const float* __restrict__ Wdst,
                       const float* __restrict__ attn_r,
                       const float* __restrict__ fcW,
                       const float* __restrict__ fcb,
                       float* __restrict__ w_er, float* __restrict__ Wn,
                       float* __restrict__ fb) {
    int t = threadIdx.x;
    if (t < 256) {
        int h0 = t >> 7, i = t & 127;
        float s = 0.f;
        for (int d = 0; d < 32; ++d)
            s += attn_r[h0 * 32 + d] * Wdst[(size_t)(h0 * 32 + d) * 128 + i];
        w_er[t] = s;
    }
    if (t < 16) {
        int oh = t >> 2, k = t & 3;
        float w[4], m = -1e30f;
        for (int j = 0; j < 4; ++j) {
            w[j] = fcW[oh * 4 + j];
            m = fmaxf(m, w[j]);
        }
        float s = 0.f;
        for (int j = 0; j < 4; ++j) s += __expf(w[j] - m);
        Wn[t] = __expf(w[k] - m) / s;
    }
    if (t < 4) fb[t] = fcb[t];
}

// ---------------------------------------------------------------------------
// K1: feat projection + el, LDS-tiled (unchanged from R3 — 878 -> ~60 us).
// ---------------------------------------------------------------------------
__global__ __launch_bounds__(256) void k_feat(
        const float* __restrict__ hier1, const float* __restrict__ Wsrc,
        const float* __restrict__ attn_l,
        float* __restrict__ feat, float* __restrict__ el, int nrows) {
    __shared__ float4 Wlds[2048];   // [kk*64 + o]
    __shared__ float4 Hlds[1024];   // [r*32 + kk]
    int t = threadIdx.x;

    const float4* W4 = reinterpret_cast<const float4*>(Wsrc);
#pragma unroll
    for (int j = 0; j < 8; ++j) {
        int g = t + j * 256;
        Wlds[(g & 31) * 64 + (g >> 5)] = W4[g];
    }
    int base = blockIdx.x * 32;
    const float4* H4 = reinterpret_cast<const float4*>(hier1);
#pragma unroll
    for (int j = 0; j < 4; ++j) {
        int idx = t + j * 256;
        int r = idx >> 5;
        if (base + r < nrows)
            Hlds[idx] = H4[(size_t)(base + r) * 32 + (idx & 31)];
    }
    __syncthreads();

    int w = t >> 6, o = t & 63;
    float al = attn_l[o];
    float acc[8];
#pragma unroll
    for (int j = 0; j < 8; ++j) acc[j] = 0.f;

    for (int kk = 0; kk < 32; ++kk) {
        float4 wv = Wlds[kk * 64 + o];
#pragma unroll
        for (int j = 0; j < 8; ++j) {
            float4 hv = Hlds[(w * 8 + j) * 32 + kk];
            acc[j] = fmaf(hv.x, wv.x,
                     fmaf(hv.y, wv.y,
                     fmaf(hv.z, wv.z,
                     fmaf(hv.w, wv.w, acc[j]))));
        }
    }

#pragma unroll
    for (int j = 0; j < 8; ++j) {
        int row = base + w * 8 + j;
        if (row < nrows) {
            feat[(size_t)row * 64 + o] = acc[j];
            float v = acc[j] * al;
#pragma unroll
            for (int m = 16; m >= 1; m >>= 1) v += __shfl_xor(v, m, 64);
            if ((o & 31) == 0) el[row * 2 + (o >> 5)] = v;
        }
    }
}

// ---------------------------------------------------------------------------
// K2: er[n,h0] = sum_i hier0[n,i] * w_er[h0,i].  One wave per node.
// ---------------------------------------------------------------------------
__global__ void k_er(const float* __restrict__ hier0,
                     const float* __restrict__ w_er, float* __restrict__ er,
                     int n) {
    int wave = (blockIdx.x * blockDim.x + threadIdx.x) >> 6;
    int lane = threadIdx.x & 63;
    if (wave >= n) return;
    float2 h = *reinterpret_cast<const float2*>(hier0 + (size_t)wave * 128 + lane * 2);
    float2 w0 = *reinterpret_cast<const float2*>(w_er + lane * 2);
    float2 w1 = *reinterpret_cast<const float2*>(w_er + 128 + lane * 2);
    float p0 = h.x * w0.x + h.y * w0.y;
    float p1 = h.x * w1.x + h.y * w1.y;
#pragma unroll
    for (int m = 32; m >= 1; m >>= 1) {
        p0 += __shfl_xor(p0, m, 64);
        p1 += __shfl_xor(p1, m, 64);
    }
    if (lane == 0) {
        er[wave * 2] = p0;
        er[wave * 2 + 1] = p1;
    }
}

// ---------------------------------------------------------------------------
// CSR build: histogram -> parallel slab alloc -> scatter.
// Slab ORDER is irrelevant to the gather (each dst only needs a contiguous
// region of size deg[d]), so we replace the serial exclusive scan with a
// per-wave prefix + one atomicAdd per wave on a global cursor.
// ---------------------------------------------------------------------------
__global__ void k_hist(const int* __restrict__ dst, int* __restrict__ deg, int E) {
    int e = blockIdx.x * blockDim.x + threadIdx.x;
    if (e < E) atomicAdd(&deg[dst[e]], 1);
}

__global__ void k_alloc(const int* __restrict__ deg, int* __restrict__ off,
                        int* __restrict__ cursor, int* __restrict__ counter,
                        int N) {
    int d = blockIdx.x * blockDim.x + threadIdx.x;
    int lane = threadIdx.x & 63;
    int v = (d < N) ? deg[d] : 0;
    int inc = v;
#pragma unroll
    for (int m = 1; m < 64; m <<= 1) {
        int u = __shfl_up(inc, m, 64);
        if (lane >= m) inc += u;
    }
    int excl = inc - v;
    int base = 0;
    if (lane == 63) base = atomicAdd(counter, inc);  // inc == wave total
    base = __shfl(base, 63, 64);
    if (d < N) {
        off[d] = base + excl;
        cursor[d] = base + excl;
    }
}

__global__ void k_scatter(const int* __restrict__ src, const int* __restrict__ dst,
                          int* __restrict__ cursor, int* __restrict__ ssrc, int E) {
    int e = blockIdx.x * blockDim.x + threadIdx.x;
    if (e >= E) return;
    int pos = atomicAdd(&cursor[dst[e]], 1);
    ssrc[pos] = src[e];
}

// ---------------------------------------------------------------------------
// K3: gather + fused epilogue.  One block (128 thr) per dst node.
// ---------------------------------------------------------------------------
__global__ __launch_bounds__(128) void k_gather(
        const int* __restrict__ ssrc, const int* __restrict__ off,
        const int* __restrict__ deg,
        const float* __restrict__ el, const float* __restrict__ er,
        const float* __restrict__ feat, const float* __restrict__ bias,
        const float* __restrict__ Wn, const float* __restrict__ fb,
        float* __restrict__ out) {
    int d = blockIdx.x;
    int t = threadIdx.x;
    int k = t >> 5, dd = t & 31;
    int start = off[d], n = deg[d];
    float erk = er[d * 2 + (k & 1)];

    float acc = 0.f, den = 0.f;
    for (int i = 0; i < n; ++i) {
        int s = ssrc[start + i];
        float ee = __expf(lrelu(el[s * 4 + k] + erk));
        den += ee;
        acc = fmaf(ee, feat[(size_t)s * 128 + t], acc);
    }

    __shared__ float g[128];
    g[t] = (den > 0.f ? acc / den : 0.f) + bias[(k & 1) * 32 + dd];
    __syncthreads();

    int oh = k;
    float r = fb[oh];
#pragma unroll
    for (int kk = 0; kk < 4; ++kk) r = fmaf(g[kk * 32 + dd], Wn[oh * 4 + kk], r);
    out[(size_t)d * 128 + oh * 32 + dd] = r;
}

// ---------------------------------------------------------------------------
extern "C" void kernel_launch(void* const* d_in, const int* in_sizes, int n_in,
                              void* d_out, int out_size, void* d_ws, size_t ws_size,
                              hipStream_t stream) {
    (void)n_in; (void)out_size; (void)ws_size;
    const float* hier1  = (const float*)d_in[0];
    const float* hier0  = (const float*)d_in[1];
    const int*   srcIdx = (const int*)d_in[2];
    const int*   dstIdx = (const int*)d_in[3];
    const float* Wsrc   = (const float*)d_in[4];
    const float* Wdst   = (const float*)d_in[5];
    const float* attn_l = (const float*)d_in[6];
    const float* attn_r = (const float*)d_in[7];
    const float* bias   = (const float*)d_in[8];
    const float* fcW    = (const float*)d_in[9];
    const float* fcb    = (const float*)d_in[10];
    float* out = (float*)d_out;

    const int Nsrc  = in_sizes[0] / 256;  // N_SRC (H1=2, IN1=128)
    const int Ndst  = in_sizes[1] / 128;  // N_DST (IN0=128)
    const int E     = in_sizes[2];
    const int nrows = Nsrc * 2;           // N_SRC * H1

    // ws layout
    float* feat    = (float*)d_ws;                  // nrows*64
    float* el      = feat + (size_t)nrows * 64;     // nrows*2
    float* er      = el   + (size_t)nrows * 2;      // Ndst*2
    float* w_er    = er   + (size_t)Ndst * 2;       // 256
    float* Wn      = w_er + 256;                    // 16
    float* fb      = Wn + 16;                       // 4
    int*  deg      = (int*)(fb + 4);                // Ndst
    int*  off      = deg + Ndst;                    // Ndst
    int*  cursor   = off + Ndst;                    // Ndst
    int*  counter  = cursor + Ndst;                 // 1
    int*  ssrc     = counter + 1;                   // E

    hipMemsetAsync(deg, 0, ((size_t)Ndst + 0) * sizeof(int), stream);
    hipMemsetAsync(counter, 0, sizeof(int), stream);

    k_prep<<<1, 256, 0, stream>>>(Wdst, attn_r, fcW, fcb, w_er, Wn, fb);

    k_feat<<<(nrows + 31) / 32, 256, 0, stream>>>(hier1, Wsrc, attn_l, feat, el, nrows);

    k_er<<<(Ndst + 3) / 4, 256, 0, stream>>>(hier0, w_er, er, Ndst);

    k_hist<<<(E + 255) / 256, 256, 0, stream>>>(dstIdx, deg, E);

    k_alloc<<<(Ndst + 255) / 256, 256, 0, stream>>>(deg, off, cursor, counter, Ndst);

    k_scatter<<<(E + 255) / 256, 256, 0, stream>>>(srcIdx, dstIdx, cursor, ssrc, E);

    k_gather<<<Ndst, 128, 0, stream>>>(ssrc, off, deg, el, er, feat, bias, Wn, fb, out);
}

// Round 5
// 671.380 us; speedup vs baseline: 2.8818x; 1.0728x over previous
//
#include <hip/hip_runtime.h>
#include <hip/hip_bf16.h>

__device__ __forceinline__ float lrelu(float x) { return x > 0.f ? x : 0.2f * x; }
__device__ __forceinline__ float blo(unsigned u) { return __uint_as_float(u << 16); }
__device__ __forceinline__ float bhi(unsigned u) { return __uint_as_float(u & 0xffff0000u); }

// ---------------------------------------------------------------------------
// K0: tiny prep — w_er[h0][i] = sum_d attn_r[h0,d]*W_dst[h0*32+d, i]  (256 vals)
//     Wn = softmax(fc_W, axis=1) (16 vals), fb = fc_b (4 vals)
// ---------------------------------------------------------------------------
__global__ void k_prep(const float* __restrict__ Wdst,
                       const float* __restrict__ attn_r,
                       const float* __restrict__ fcW,
                       const float* __restrict__ fcb,
                       float* __restrict__ w_er, float* __restrict__ Wn,
                       float* __restrict__ fb) {
    int t = threadIdx.x;
    if (t < 256) {
        int h0 = t >> 7, i = t & 127;
        float s = 0.f;
        for (int d = 0; d < 32; ++d)
            s += attn_r[h0 * 32 + d] * Wdst[(size_t)(h0 * 32 + d) * 128 + i];
        w_er[t] = s;
    }
    if (t < 16) {
        int oh = t >> 2, k = t & 3;
        float w[4], m = -1e30f;
        for (int j = 0; j < 4; ++j) {
            w[j] = fcW[oh * 4 + j];
            m = fmaxf(m, w[j]);
        }
        float s = 0.f;
        for (int j = 0; j < 4; ++j) s += __expf(w[j] - m);
        Wn[t] = __expf(w[k] - m) / s;
    }
    if (t < 4) fb[t] = fcb[t];
}

// ---------------------------------------------------------------------------
// Phase A: feat projection (bf16 out) + el  +  fused hist (1 edge/thread)
//          +  fused er (grid-stride, wave per node).
//   feat bf16 layout: node n has 128 bf16 = cols h1*64 + h0*32 + dd.
// ---------------------------------------------------------------------------
__global__ __launch_bounds__(256) void k_featA(
        const float* __restrict__ hier1, const float* __restrict__ Wsrc,
        const float* __restrict__ attn_l,
        const float* __restrict__ hier0, const float* __restrict__ w_er,
        const int* __restrict__ dstIdx,
        __hip_bfloat16* __restrict__ featb, float* __restrict__ el,
        float* __restrict__ er, int* __restrict__ deg,
        int nrows, int Ndst, int E) {
    __shared__ float4 Wlds[2048];   // [kk*64 + o]
    __shared__ float4 Hlds[1024];   // [r*32 + kk]
    int t = threadIdx.x;

    // --- fused hist: one edge per thread (independent of the rest) ---
    {
        int e = blockIdx.x * 256 + t;
        if (e < E) atomicAdd(&deg[dstIdx[e]], 1);
    }

    // --- feat tile ---
    const float4* W4 = reinterpret_cast<const float4*>(Wsrc);
#pragma unroll
    for (int j = 0; j < 8; ++j) {
        int g = t + j * 256;
        Wlds[(g & 31) * 64 + (g >> 5)] = W4[g];
    }
    int base = blockIdx.x * 32;
    const float4* H4 = reinterpret_cast<const float4*>(hier1);
#pragma unroll
    for (int j = 0; j < 4; ++j) {
        int idx = t + j * 256;
        int r = idx >> 5;
        if (base + r < nrows)
            Hlds[idx] = H4[(size_t)(base + r) * 32 + (idx & 31)];
    }
    __syncthreads();

    int w = t >> 6, o = t & 63;
    float al = attn_l[o];
    float acc[8];
#pragma unroll
    for (int j = 0; j < 8; ++j) acc[j] = 0.f;

    for (int kk = 0; kk < 32; ++kk) {
        float4 wv = Wlds[kk * 64 + o];
#pragma unroll
        for (int j = 0; j < 8; ++j) {
            float4 hv = Hlds[(w * 8 + j) * 32 + kk];
            acc[j] = fmaf(hv.x, wv.x,
                     fmaf(hv.y, wv.y,
                     fmaf(hv.z, wv.z,
                     fmaf(hv.w, wv.w, acc[j]))));
        }
    }

#pragma unroll
    for (int j = 0; j < 8; ++j) {
        int row = base + w * 8 + j;
        if (row < nrows) {
            // row = n*2 + h1 -> featb[n*128 + h1*64 + o]
            featb[((size_t)(row >> 1)) * 128 + (row & 1) * 64 + o] =
                __float2bfloat16(acc[j]);
            float v = acc[j] * al;
#pragma unroll
            for (int m = 16; m >= 1; m >>= 1) v += __shfl_xor(v, m, 64);
            if ((o & 31) == 0) el[row * 2 + (o >> 5)] = v;
        }
    }

    // --- fused er: wave per node, grid-stride ---
    int lane = t & 63;
    int gw = blockIdx.x * 4 + w;
    int nwaves = gridDim.x * 4;
    float2 w0 = *reinterpret_cast<const float2*>(w_er + lane * 2);
    float2 w1 = *reinterpret_cast<const float2*>(w_er + 128 + lane * 2);
    for (int node = gw; node < Ndst; node += nwaves) {
        float2 h = *reinterpret_cast<const float2*>(hier0 + (size_t)node * 128 + lane * 2);
        float p0 = h.x * w0.x + h.y * w0.y;
        float p1 = h.x * w1.x + h.y * w1.y;
#pragma unroll
        for (int m = 32; m >= 1; m >>= 1) {
            p0 += __shfl_xor(p0, m, 64);
            p1 += __shfl_xor(p1, m, 64);
        }
        if (lane == 0) {
            er[node * 2] = p0;
            er[node * 2 + 1] = p1;
        }
    }
}

// ---------------------------------------------------------------------------
// Slab alloc: per-wave prefix + one atomicAdd per wave (order irrelevant).
// ---------------------------------------------------------------------------
__global__ void k_alloc(const int* __restrict__ deg, int* __restrict__ off,
                        int* __restrict__ cursor, int* __restrict__ counter,
                        int N) {
    int d = blockIdx.x * blockDim.x + threadIdx.x;
    int lane = threadIdx.x & 63;
    int v = (d < N) ? deg[d] : 0;
    int inc = v;
#pragma unroll
    for (int m = 1; m < 64; m <<= 1) {
        int u = __shfl_up(inc, m, 64);
        if (lane >= m) inc += u;
    }
    int excl = inc - v;
    int base = 0;
    if (lane == 63) base = atomicAdd(counter, inc);
    base = __shfl(base, 63, 64);
    if (d < N) {
        off[d] = base + excl;
        cursor[d] = base + excl;
    }
}

__global__ void k_scatter(const int* __restrict__ src, const int* __restrict__ dst,
                          int* __restrict__ cursor, int* __restrict__ ssrc, int E) {
    int e = blockIdx.x * blockDim.x + threadIdx.x;
    if (e >= E) return;
    int pos = atomicAdd(&cursor[dst[e]], 1);
    ssrc[pos] = src[e];
}

// ---------------------------------------------------------------------------
// Gather + fused epilogue.  ONE WAVE per dst (4 dsts per 256-block).
//   Lane l covers feat cols 2l, 2l+1 (one uint of bf16x2):
//     k = l>>4 (h1*2+h0), dd = 2*(l&15).
//   Per edge: ee = exp(lrelu(el[s,k]+er[d,h0])), acc += ee*feat (2 cols),
//   den += ee (redundant across 16 lanes of same k — free).
//   Epilogue: g -> LDS, remap lane -> out cols 2l,2l+1 (oh=l>>4), float2 store.
// ---------------------------------------------------------------------------
__global__ __launch_bounds__(256) void k_gather(
        const int* __restrict__ ssrc, const int* __restrict__ off,
        const int* __restrict__ deg,
        const float* __restrict__ el, const float* __restrict__ er,
        const unsigned* __restrict__ featb,
        const float* __restrict__ bias,
        const float* __restrict__ Wn, const float* __restrict__ fb,
        float* __restrict__ out, int Ndst) {
    __shared__ float g[4][128];
    int t = threadIdx.x;
    int wv = t >> 6, lane = t & 63;
    int d = blockIdx.x * 4 + wv;
    bool valid = d < Ndst;

    int k = lane >> 4;
    int dd = (lane & 15) * 2;
    float erk = valid ? er[d * 2 + (k & 1)] : 0.f;
    int start = valid ? off[d] : 0;
    int n = valid ? deg[d] : 0;

    float a0 = 0.f, a1 = 0.f, den = 0.f;
    int s = (n > 0) ? ssrc[start] : 0;
    for (int i = 0; i < n; ++i) {
        int snext = (i + 1 < n) ? ssrc[start + i + 1] : 0;
        unsigned f2 = featb[(size_t)s * 64 + lane];
        float ee = __expf(lrelu(el[s * 4 + k] + erk));
        den += ee;
        a0 = fmaf(ee, blo(f2), a0);
        a1 = fmaf(ee, bhi(f2), a1);
        s = snext;
    }

    float inv = den > 0.f ? 1.f / den : 0.f;
    float b = bias[(k & 1) * 32 + dd];
    float b1 = bias[(k & 1) * 32 + dd + 1];
    g[wv][k * 32 + dd] = a0 * inv + b;
    g[wv][k * 32 + dd + 1] = a1 * inv + b1;
    __syncthreads();

    if (valid) {
        int oh = lane >> 4;      // out cols 2l,2l+1 -> oh = (2l)>>5
        float r0 = fb[oh], r1 = r0;
#pragma unroll
        for (int kk = 0; kk < 4; ++kk) {
            float wgt = Wn[oh * 4 + kk];
            r0 = fmaf(g[wv][kk * 32 + dd], wgt, r0);
            r1 = fmaf(g[wv][kk * 32 + dd + 1], wgt, r1);
        }
        *reinterpret_cast<float2*>(out + (size_t)d * 128 + lane * 2) =
            make_float2(r0, r1);
    }
}

// ---------------------------------------------------------------------------
extern "C" void kernel_launch(void* const* d_in, const int* in_sizes, int n_in,
                              void* d_out, int out_size, void* d_ws, size_t ws_size,
                              hipStream_t stream) {
    (void)n_in; (void)out_size; (void)ws_size;
    const float* hier1  = (const float*)d_in[0];
    const float* hier0  = (const float*)d_in[1];
    const int*   srcIdx = (const int*)d_in[2];
    const int*   dstIdx = (const int*)d_in[3];
    const float* Wsrc   = (const float*)d_in[4];
    const float* Wdst   = (const float*)d_in[5];
    const float* attn_l = (const float*)d_in[6];
    const float* attn_r = (const float*)d_in[7];
    const float* bias   = (const float*)d_in[8];
    const float* fcW    = (const float*)d_in[9];
    const float* fcb    = (const float*)d_in[10];
    float* out = (float*)d_out;

    const int Nsrc  = in_sizes[0] / 256;  // N_SRC (H1=2, IN1=128)
    const int Ndst  = in_sizes[1] / 128;  // N_DST (IN0=128)
    const int E     = in_sizes[2];
    const int nrows = Nsrc * 2;           // N_SRC * H1

    // ws layout
    __hip_bfloat16* featb = (__hip_bfloat16*)d_ws;        // Nsrc*128 bf16
    float* el   = (float*)(featb + (size_t)Nsrc * 128);   // nrows*2
    float* er   = el   + (size_t)nrows * 2;               // Ndst*2
    float* w_er = er   + (size_t)Ndst * 2;                // 256
    float* Wn   = w_er + 256;                             // 16
    float* fb   = Wn + 16;                                // 4
    int*  deg     = (int*)(fb + 4);                       // Ndst
    int*  off     = deg + Ndst;                           // Ndst
    int*  cursor  = off + Ndst;                           // Ndst
    int*  counter = cursor + Ndst;                        // 1
    int*  ssrc    = counter + 1;                          // E

    hipMemsetAsync(deg, 0, (size_t)Ndst * sizeof(int), stream);
    hipMemsetAsync(counter, 0, sizeof(int), stream);

    k_prep<<<1, 256, 0, stream>>>(Wdst, attn_r, fcW, fcb, w_er, Wn, fb);

    int blocksA = (nrows + 31) / 32;
    int blocksE = (E + 255) / 256;
    if (blocksE > blocksA) blocksA = blocksE;
    k_featA<<<blocksA, 256, 0, stream>>>(hier1, Wsrc, attn_l, hier0, w_er,
                                         dstIdx, featb, el, er, deg,
                                         nrows, Ndst, E);

    k_alloc<<<(Ndst + 255) / 256, 256, 0, stream>>>(deg, off, cursor, counter, Ndst);

    k_scatter<<<(E + 255) / 256, 256, 0, stream>>>(srcIdx, dstIdx, cursor, ssrc, E);

    k_gather<<<(Ndst + 3) / 4, 256, 0, stream>>>(ssrc, off, deg, el, er,
                                                 (const unsigned*)featb,
                                                 bias, Wn, fb, out, Ndst);
}